// Round 10
// baseline (17269.699 us; speedup 1.0000x reference)
//
#include <hip/hip_runtime.h>
#include <hip/hip_bf16.h>

#define NN 100000
#define EE 1600000
#define RR 6
#define NBK 391        // dst/src buckets of 256 nodes
#define EB 391         // edge blocks (4096 edges each)
#define CAP 4608       // per-bucket edge capacity (mean 4096, +8 sigma)

typedef __attribute__((ext_vector_type(8))) short bf16x8;
typedef __attribute__((ext_vector_type(4))) float f32x4;

__device__ inline short f2b(float x) {
    __hip_bfloat16 h = __float2bfloat16(x);
    return *reinterpret_cast<short*>(&h);
}
__device__ inline float b2f(short s) {
    __hip_bfloat16 h = *reinterpret_cast<__hip_bfloat16*>(&s);
    return __bfloat162float(h);
}
__device__ inline float bu2f(unsigned short u) {
    return __uint_as_float((unsigned)u << 16);
}

// ---------------- edge bucketing (no CSR) ----------------

__global__ __launch_bounds__(256) void zero_cnts(int* p, int n) {
    int i = blockIdx.x * 256 + threadIdx.x;
    if (i < n) p[i] = 0;
}

// scatter edges into fixed-capacity dst-bucket regions (pairs: src<<8|dstLocal)
// and src-bucket regions (srcs u8) -- LDS chunk aggregation, no pre-count pass.
__global__ __launch_bounds__(256) void bin_scatter(const int* __restrict__ src,
                                                   const int* __restrict__ dst,
                                                   int* __restrict__ bcurD,
                                                   int* __restrict__ bcurS,
                                                   unsigned* __restrict__ pairs,
                                                   unsigned char* __restrict__ srcs) {
    __shared__ int lcD[NBK], lbD[NBK], loD[NBK];
    __shared__ int lcS[NBK], lbS[NBK], loS[NBK];
    int t = threadIdx.x;
    for (int i = t; i < NBK; i += 256) { lcD[i] = 0; loD[i] = 0; lcS[i] = 0; loS[i] = 0; }
    __syncthreads();
    int base = blockIdx.x * 4096;
#pragma unroll
    for (int i = 0; i < 16; ++i) {
        int e = base + i * 256 + t;
        if (e < EE) {
            atomicAdd(&lcD[dst[e] >> 8], 1);
            atomicAdd(&lcS[src[e] >> 8], 1);
        }
    }
    __syncthreads();
    for (int i = t; i < NBK; i += 256) {
        lbD[i] = lcD[i] ? atomicAdd(&bcurD[i], lcD[i]) : 0;
        lbS[i] = lcS[i] ? atomicAdd(&bcurS[i], lcS[i]) : 0;
    }
    __syncthreads();
#pragma unroll
    for (int i = 0; i < 16; ++i) {
        int e = base + i * 256 + t;
        if (e < EE) {
            int s = src[e], d = dst[e];
            int bD = d >> 8, bS = s >> 8;
            int pD = lbD[bD] + atomicAdd(&loD[bD], 1);
            if (pD >= 0 && pD < CAP)
                pairs[(size_t)bD * CAP + pD] = ((unsigned)s << 8) | (unsigned)(d & 255);
            int pS = lbS[bS] + atomicAdd(&loS[bS], 1);
            if (pS >= 0 && pS < CAP)
                srcs[(size_t)bS * CAP + pS] = (unsigned char)(s & 255);
        }
    }
}

// one block per src-bucket: LDS hist -> dis = rsqrt(deg)
__global__ __launch_bounds__(256) void deg_dis(const unsigned char* __restrict__ srcs,
                                               const int* __restrict__ bcurS,
                                               float* __restrict__ dis) {
    __shared__ int hist[256];
    int b = blockIdx.x, t = threadIdx.x;
    hist[t] = 0;
    __syncthreads();
    int cnt = min(bcurS[b], CAP);
    const unsigned char* sp = srcs + (size_t)b * CAP;
    for (int e = t; e < cnt; e += 256)
        atomicAdd(&hist[sp[e]], 1);
    __syncthreads();
    int node = b * 256 + t;
    if (node < NN) {
        int d = hist[t];
        dis[node] = d > 0 ? rsqrtf((float)d) : 0.f;
    }
}

// ---------------- SpMM: edge-streaming into LDS f32 accumulators ----------------
// MID=1: outb[row,:] = bf16( y1b[row,:] - 2*dis^2 * sum v[src,:] )
// MID=0: outb[row,:] = bf16( -dis * sum v[src,:] )
template <int MID>
__global__ __launch_bounds__(512) void spmm_lds(const unsigned* __restrict__ pairs,
                                                const int* __restrict__ ecnt,
                                                const short* __restrict__ v,
                                                const short* __restrict__ y1b,
                                                short* __restrict__ outb,
                                                const float* __restrict__ dis) {
    __shared__ float acc[256 * 64];   // 64 KB
    int b = blockIdx.x;
    int t = threadIdx.x;
    for (int i = t; i < 4096; i += 512)
        ((f32x4*)acc)[i] = (f32x4){0.f, 0.f, 0.f, 0.f};
    __syncthreads();
    int cnt = min(ecnt[b], CAP);
    const unsigned* pb = pairs + (size_t)b * CAP;
    int w = t >> 6, l = t & 63, h = l >> 5, fl = l & 31;
    int hw = w * 2 + h;               // half-wave id 0..15
    int e0 = hw * 8;
    for (; e0 + 8 <= cnt; e0 += 128) {
        unsigned pr[8];
#pragma unroll
        for (int i = 0; i < 8; ++i) pr[i] = pb[e0 + i];
        unsigned short a[8], c[8];
#pragma unroll
        for (int i = 0; i < 8; ++i) {
            const short* vp = v + (size_t)(pr[i] >> 8) * 64 + fl;
            a[i] = *(const unsigned short*)vp;
            c[i] = *(const unsigned short*)(vp + 32);
        }
#pragma unroll
        for (int i = 0; i < 8; ++i) {
            int dl = pr[i] & 255;
            atomicAdd(&acc[dl * 64 + fl], bu2f(a[i]));
            atomicAdd(&acc[dl * 64 + 32 + fl], bu2f(c[i]));
        }
    }
    for (int e = e0; e < cnt; ++e) {
        unsigned pr = pb[e];
        const short* vp = v + (size_t)(pr >> 8) * 64 + fl;
        unsigned short a = *(const unsigned short*)vp;
        unsigned short c = *(const unsigned short*)(vp + 32);
        int dl = pr & 255;
        atomicAdd(&acc[dl * 64 + fl], bu2f(a));
        atomicAdd(&acc[dl * 64 + 32 + fl], bu2f(c));
    }
    __syncthreads();
    int rows_in = min(256, NN - b * 256);
    for (int i = t; i < rows_in * 32; i += 512) {
        int rl = i >> 5, c2 = (i & 31) * 2;
        int row = b * 256 + rl;
        float d = dis[row];
        float a0 = acc[rl * 64 + c2], a1 = acc[rl * 64 + c2 + 1];
        float v0, v1;
        if (MID) {
            unsigned yu = *(const unsigned*)(y1b + (size_t)row * 64 + c2);
            float mm = -2.f * d * d;
            v0 = __uint_as_float(yu << 16) + mm * a0;
            v1 = __uint_as_float(yu & 0xffff0000u) + mm * a1;
        } else {
            v0 = -d * a0;
            v1 = -d * a1;
        }
        unsigned o = (unsigned)(unsigned short)f2b(v0) | ((unsigned)(unsigned short)f2b(v1) << 16);
        *(unsigned*)(outb + (size_t)row * 64 + c2) = o;
    }
}

// ---------------- x -> bf16 once ----------------
__global__ __launch_bounds__(256) void cvt_x(const float* __restrict__ x, short* __restrict__ xb) {
    int i = blockIdx.x * 256 + threadIdx.x;   // per 8 elems
    if (i >= NN * 128 / 8) return;
    const float* p = x + (size_t)i * 8;
    float4 u0 = *(const float4*)p;
    float4 u1 = *(const float4*)(p + 4);
    bf16x8 t;
    t[0] = f2b(u0.x); t[1] = f2b(u0.y); t[2] = f2b(u0.z); t[3] = f2b(u0.w);
    t[4] = f2b(u1.x); t[5] = f2b(u1.y); t[6] = f2b(u1.z); t[7] = f2b(u1.w);
    *(bf16x8*)(xb + (size_t)i * 8) = t;
}

// ---------------- weight packing into MFMA B-fragment order, hi/lo bf16 ----------------
__global__ __launch_bounds__(256) void wpack_cheb(const float* __restrict__ W, int Kin, int KS,
                                                  short* __restrict__ bh, short* __restrict__ bl) {
    int idx = blockIdx.x * 256 + threadIdx.x;   // over R*12*KS*64
    int l = idx & 63;
    int q = idx >> 6;
    int s = q % KS; q /= KS;
    int t = q % 12; q /= 12;
    int r = q;
    if (r >= RR) return;
#pragma unroll
    for (int j = 0; j < 8; ++j) {
        int k = s * 32 + ((l >> 4) * 8) + j;
        int n = t * 16 + (l & 15);
        int g = n >> 6, jj = n & 63;
        float v = W[(((size_t)r * 3 + (g == 0 ? 0 : g)) * Kin + k) * 64 + jj];
        if (g == 0) v -= W[(((size_t)r * 3 + 2) * Kin + k) * 64 + jj];
        short hi = f2b(v);
        short lo = f2b(v - b2f(hi));
        bh[(size_t)idx * 8 + j] = hi;
        bl[(size_t)idx * 8 + j] = lo;
    }
}

__global__ __launch_bounds__(256) void wpack64(const float* __restrict__ W,
                                               short* __restrict__ bh, short* __restrict__ bl) {
    int idx = blockIdx.x * 256 + threadIdx.x;   // over 4*2*64 = 512
    if (idx >= 512) return;
    int l = idx & 63;
    int s = (idx >> 6) & 1;
    int t = idx >> 7;
#pragma unroll
    for (int j = 0; j < 8; ++j) {
        int k = s * 32 + ((l >> 4) * 8) + j;
        int n = t * 16 + (l & 15);
        float v = W[k * 64 + n];
        short hi = f2b(v);
        short lo = f2b(v - b2f(hi));
        bh[(size_t)idx * 8 + j] = hi;
        bl[(size_t)idx * 8 + j] = lo;
    }
}

// ---------------- MFMA GEMM (A bf16, up to 3 bf16 outputs) ----------------
// tiles t<s1 -> o0, t<s2 -> o1, else o2. rowscale applied only to tiles >= scale_from.
template <int KDIM>
__global__ __launch_bounds__(256) void gemm_mfma(const short* __restrict__ A, int lda,
                                                 const short* __restrict__ bph,
                                                 const short* __restrict__ bplo,
                                                 int nt0, int ntn, int s1, int s2,
                                                 short* __restrict__ o0, int ld0,
                                                 short* __restrict__ o1, int ld1,
                                                 short* __restrict__ o2, int ld2,
                                                 const float* __restrict__ bias,
                                                 int scale_from,
                                                 const float* __restrict__ rowscale,
                                                 int do_relu) {
    constexpr int KS = KDIM / 32;
    int w = threadIdx.x >> 6, l = threadIdx.x & 63;
    int rows0 = blockIdx.x * 64 + w * 16;
    int arow = rows0 + (l & 15);
    int kbase = (l >> 4) * 8;
    bf16x8 af[KS];
#pragma unroll
    for (int s = 0; s < KS; ++s) {
        bf16x8 t = {0, 0, 0, 0, 0, 0, 0, 0};
        if (arow < NN) t = *(const bf16x8*)(A + (size_t)arow * lda + s * 32 + kbase);
        af[s] = t;
    }
    for (int t = 0; t < ntn; ++t) {
        f32x4 acc = {0.f, 0.f, 0.f, 0.f};
        const short* bp0 = bph + (((size_t)(nt0 + t) * KS) * 64 + l) * 8;
        const short* bl0 = bplo + (((size_t)(nt0 + t) * KS) * 64 + l) * 8;
#pragma unroll
        for (int s = 0; s < KS; ++s) {
            bf16x8 bh = *(const bf16x8*)(bp0 + (size_t)s * 64 * 8);
            bf16x8 bl = *(const bf16x8*)(bl0 + (size_t)s * 64 * 8);
            acc = __builtin_amdgcn_mfma_f32_16x16x32_bf16(af[s], bh, acc, 0, 0, 0);
            acc = __builtin_amdgcn_mfma_f32_16x16x32_bf16(af[s], bl, acc, 0, 0, 0);
        }
        short* o;
        int ldc, tl;
        if (t < s1) { o = o0; ldc = ld0; tl = t; }
        else if (t < s2) { o = o1; ldc = ld1; tl = t - s1; }
        else { o = o2; ldc = ld2; tl = t - s2; }
        int lcol = (tl << 4) + (l & 15);
        bool scl = (rowscale != nullptr) && (t >= scale_from);
#pragma unroll
        for (int r_ = 0; r_ < 4; ++r_) {
            int row = rows0 + (l >> 4) * 4 + r_;
            if (row >= NN) continue;
            float v = acc[r_];
            if (bias) v += bias[lcol];
            if (do_relu) v = fmaxf(v, 0.f);
            if (scl) v *= rowscale[row];
            o[(size_t)row * ldc + lcol] = f2b(v);
        }
    }
}

// ---------------- elementwise: out = relu(t0 + s + bias), bf16 in/out ----------------
__global__ __launch_bounds__(256) void ew_h(const short* __restrict__ t0,
                                            const short* __restrict__ s,
                                            const float* __restrict__ bias,
                                            short* __restrict__ out, int ldc) {
    int i = blockIdx.x * 256 + threadIdx.x;   // over NN*32 u32 groups
    if (i >= NN * 32) return;
    int row = i >> 5, c2 = (i & 31) * 2;
    unsigned a = *(const unsigned*)(t0 + (size_t)row * 64 + c2);
    unsigned b = *(const unsigned*)(s + (size_t)row * 64 + c2);
    float v0 = __uint_as_float(a << 16) + __uint_as_float(b << 16) + bias[c2];
    float v1 = __uint_as_float(a & 0xffff0000u) + __uint_as_float(b & 0xffff0000u) + bias[c2 + 1];
    v0 = fmaxf(v0, 0.f);
    v1 = fmaxf(v1, 0.f);
    unsigned o = (unsigned)(unsigned short)f2b(v0) | ((unsigned)(unsigned short)f2b(v1) << 16);
    *(unsigned*)(out + (size_t)row * ldc + c2) = o;
}

// ---------------- gate via MFMA (+ fused aux outputs) ----------------
__global__ __launch_bounds__(256) void gate_mfma(const short* __restrict__ stack,
                                                 const short* __restrict__ g1h,
                                                 const short* __restrict__ g1l,
                                                 const float* __restrict__ gb1,
                                                 const float* __restrict__ gw2,
                                                 const float* __restrict__ gb2,
                                                 const float* __restrict__ auxw,
                                                 const float* __restrict__ auxb,
                                                 float* __restrict__ glogit,
                                                 float* __restrict__ out) {
    int w = threadIdx.x >> 6, l = threadIdx.x & 63;
    int rows0 = blockIdx.x * 64 + w * 16;      // 9375*64 == 600000 exactly
    int arow = rows0 + (l & 15);
    int kbase = (l >> 4) * 8;
    bf16x8 af[2];
#pragma unroll
    for (int s = 0; s < 2; ++s)
        af[s] = *(const bf16x8*)(stack + (size_t)arow * 64 + s * 32 + kbase);
    int rmod = arow % RR;
    float paux = 0.f;
#pragma unroll
    for (int s = 0; s < 2; ++s) {
        const float* aw = auxw + rmod * 64 + s * 32 + kbase;
#pragma unroll
        for (int j = 0; j < 8; ++j) paux = fmaf(b2f(af[s][j]), aw[j], paux);
    }
    paux += __shfl_xor(paux, 16, 64);
    paux += __shfl_xor(paux, 32, 64);
    if (l < 16) out[NN + (size_t)rows0 + l] = paux + auxb[rmod];
    float p[4] = {0.f, 0.f, 0.f, 0.f};
#pragma unroll
    for (int t = 0; t < 4; ++t) {
        f32x4 acc = {0.f, 0.f, 0.f, 0.f};
#pragma unroll
        for (int s = 0; s < 2; ++s) {
            bf16x8 bh = *(const bf16x8*)(g1h + (((size_t)t * 2 + s) * 64 + l) * 8);
            bf16x8 bl = *(const bf16x8*)(g1l + (((size_t)t * 2 + s) * 64 + l) * 8);
            acc = __builtin_amdgcn_mfma_f32_16x16x32_bf16(af[s], bh, acc, 0, 0, 0);
            acc = __builtin_amdgcn_mfma_f32_16x16x32_bf16(af[s], bl, acc, 0, 0, 0);
        }
        int col = t * 16 + (l & 15);
        float b = gb1[col], w2 = gw2[col];
#pragma unroll
        for (int r_ = 0; r_ < 4; ++r_) {
            float h = fmaxf(acc[r_] + b, 0.f);
            p[r_] = fmaf(h, w2, p[r_]);
        }
    }
#pragma unroll
    for (int d = 1; d < 16; d <<= 1) {
#pragma unroll
        for (int r_ = 0; r_ < 4; ++r_) p[r_] += __shfl_xor(p[r_], d, 64);
    }
    if ((l & 15) == 0) {
        float g2 = gb2[0];
#pragma unroll
        for (int r_ = 0; r_ < 4; ++r_) glogit[rows0 + (l >> 4) * 4 + r_] = p[r_] + g2;
    }
}

// ---------------- fuse: softmax over R -> h_fused (bf16) ----------------
__global__ __launch_bounds__(256) void fuse_kernel(const short* __restrict__ stack,
                                                   const float* __restrict__ glogit,
                                                   short* __restrict__ hfused) {
    int tid = threadIdx.x;
    int w = tid >> 6, lane = tid & 63;
    int n = blockIdx.x * 4 + w;
    if (n >= NN) return;
    float gl[RR];
    float m = -1e30f;
#pragma unroll
    for (int r = 0; r < RR; r++) {
        gl[r] = glogit[(size_t)n * RR + r];
        m = fmaxf(m, gl[r]);
    }
    float ssum = 0.f;
#pragma unroll
    for (int r = 0; r < RR; r++) {
        gl[r] = __expf(gl[r] - m);
        ssum += gl[r];
    }
    float inv = 1.f / ssum;
    float hf = 0.f;
#pragma unroll
    for (int r = 0; r < RR; r++) {
        float s = b2f(stack[((size_t)n * RR + r) * 64 + lane]);
        hf = fmaf(gl[r] * inv, s, hf);
    }
    hfused[(size_t)n * 64 + lane] = f2b(hf);
}

// ---------------- cls via MFMA ----------------
__global__ __launch_bounds__(256) void cls_mfma(const short* __restrict__ hproj,
                                                const short* __restrict__ c1h,
                                                const short* __restrict__ c1l,
                                                const float* __restrict__ cb1,
                                                const float* __restrict__ cw2,
                                                const float* __restrict__ cb2,
                                                float* __restrict__ out) {
    int w = threadIdx.x >> 6, l = threadIdx.x & 63;
    int rows0 = blockIdx.x * 64 + w * 16;
    int arow = rows0 + (l & 15);
    int kbase = (l >> 4) * 8;
    bf16x8 af[2];
#pragma unroll
    for (int s = 0; s < 2; ++s) {
        bf16x8 t = {0, 0, 0, 0, 0, 0, 0, 0};
        if (arow < NN) t = *(const bf16x8*)(hproj + (size_t)arow * 64 + s * 32 + kbase);
        af[s] = t;
    }
    float p[4] = {0.f, 0.f, 0.f, 0.f};
#pragma unroll
    for (int t = 0; t < 4; ++t) {
        f32x4 acc = {0.f, 0.f, 0.f, 0.f};
#pragma unroll
        for (int s = 0; s < 2; ++s) {
            bf16x8 bh = *(const bf16x8*)(c1h + (((size_t)t * 2 + s) * 64 + l) * 8);
            bf16x8 bl = *(const bf16x8*)(c1l + (((size_t)t * 2 + s) * 64 + l) * 8);
            acc = __builtin_amdgcn_mfma_f32_16x16x32_bf16(af[s], bh, acc, 0, 0, 0);
            acc = __builtin_amdgcn_mfma_f32_16x16x32_bf16(af[s], bl, acc, 0, 0, 0);
        }
        int col = t * 16 + (l & 15);
        float b = cb1[col], w2 = cw2[col];
#pragma unroll
        for (int r_ = 0; r_ < 4; ++r_) {
            float h = fmaxf(acc[r_] + b, 0.f);
            p[r_] = fmaf(h, w2, p[r_]);
        }
    }
#pragma unroll
    for (int d = 1; d < 16; d <<= 1) {
#pragma unroll
        for (int r_ = 0; r_ < 4; ++r_) p[r_] += __shfl_xor(p[r_], d, 64);
    }
    if ((l & 15) == 0) {
        float c2 = cb2[0];
#pragma unroll
        for (int r_ = 0; r_ < 4; ++r_) {
            int row = rows0 + (l >> 4) * 4 + r_;
            if (row < NN) out[row] = p[r_] + c2;
        }
    }
}

// ---------------- host ----------------

extern "C" void kernel_launch(void* const* d_in, const int* in_sizes, int n_in,
                              void* d_out, int out_size, void* d_ws, size_t ws_size,
                              hipStream_t stream) {
    const float* x = (const float*)d_in[0];
    const int* ei = (const int*)d_in[1];
    const float* c1w = (const float*)d_in[2];
    const float* c1b = (const float*)d_in[3];
    const float* c2w = (const float*)d_in[4];
    const float* c2b = (const float*)d_in[5];
    const float* gw1 = (const float*)d_in[6];
    const float* gb1 = (const float*)d_in[7];
    const float* gw2 = (const float*)d_in[8];
    const float* gb2 = (const float*)d_in[9];
    const float* pw = (const float*)d_in[10];
    const float* pb = (const float*)d_in[11];
    const float* cw1 = (const float*)d_in[12];
    const float* cb1 = (const float*)d_in[13];
    const float* cw2 = (const float*)d_in[14];
    const float* cb2 = (const float*)d_in[15];
    const float* auxw = (const float*)d_in[16];
    const float* auxb = (const float*)d_in[17];
    float* out = (float*)d_out;

    char* wsp = (char*)d_ws;
    size_t off = 0;
    auto carve = [&](size_t bytes) -> char* {
        char* p = wsp + off;
        off += (bytes + 255) & ~(size_t)255;
        return p;
    };
    short* stack = (short*)carve((size_t)NN * RR * 64 * 2);   // bf16 [N][R][64]
    short* y1b = (short*)carve((size_t)NN * 64 * 2);          // y1' bf16; aliases zb
    short* y2b = (short*)carve((size_t)NN * 64 * 2);          // y2' bf16; aliases hproj
    short* wb = (short*)carve((size_t)NN * 64 * 2);           // w' bf16; aliases srcs
    short* h1 = (short*)carve((size_t)NN * 64 * 2);           // bf16; also hfused
    short* t0b = (short*)carve((size_t)NN * 64 * 2);          // x@(W0-W2) bf16
    short* xb = (short*)carve((size_t)NN * 128 * 2);          // x as bf16
    float* dis = (float*)carve((size_t)NN * 4);
    unsigned* pairs = (unsigned*)carve((size_t)NBK * CAP * 4);  // persists per relation
    int* cnts = (int*)carve((size_t)2 * RR * NBK * 4);        // bcurD|bcurS per relation
    short* bp1h = (short*)carve((size_t)RR * 12 * 4 * 64 * 8 * 2);
    short* bp1l = (short*)carve((size_t)RR * 12 * 4 * 64 * 8 * 2);
    short* bp2h = (short*)carve((size_t)RR * 12 * 2 * 64 * 8 * 2);
    short* bp2l = (short*)carve((size_t)RR * 12 * 2 * 64 * 8 * 2);
    short* g1h = (short*)carve((size_t)512 * 8 * 2);
    short* g1l = (short*)carve((size_t)512 * 8 * 2);
    short* pwh = (short*)carve((size_t)512 * 8 * 2);
    short* pwl = (short*)carve((size_t)512 * 8 * 2);
    short* c1h = (short*)carve((size_t)512 * 8 * 2);
    short* c1l = (short*)carve((size_t)512 * 8 * 2);
    float* glogit = (float*)carve((size_t)NN * RR * 4);
    short* zb = y1b;                                // alias: y1' consumed by spmm<1> first
    unsigned char* srcs = (unsigned char*)wb;       // NBK*CAP u8 = 1.8MB <= wb 12.8MB
    short* hfused = h1;       // alias: h1 dead after relation loop
    short* hproj = y2b;       // alias: y2b dead after relation loop
    (void)in_sizes; (void)n_in; (void)out_size;

    if (off > ws_size) return;   // guard: clean absmax-fail => ws too small

    zero_cnts<<<(2 * RR * NBK + 255) / 256, 256, 0, stream>>>(cnts, 2 * RR * NBK);
    cvt_x<<<(NN * 128 / 8 + 255) / 256, 256, 0, stream>>>(x, xb);
    wpack_cheb<<<72, 256, 0, stream>>>(c1w, 128, 4, bp1h, bp1l);
    wpack_cheb<<<36, 256, 0, stream>>>(c2w, 64, 2, bp2h, bp2l);
    wpack64<<<2, 256, 0, stream>>>(gw1, g1h, g1l);
    wpack64<<<2, 256, 0, stream>>>(pw, pwh, pwl);
    wpack64<<<2, 256, 0, stream>>>(cw1, c1h, c1l);

    const int GB = 1563;   // ceil(NN/64)
    for (int r = 0; r < RR; ++r) {
        const int* src = ei + (size_t)r * 2 * EE;
        const int* dst = src + EE;
        const short* b1h = bp1h + (size_t)r * 12 * 4 * 64 * 8;
        const short* b1l = bp1l + (size_t)r * 12 * 4 * 64 * 8;
        const short* b2h = bp2h + (size_t)r * 12 * 2 * 64 * 8;
        const short* b2l = bp2l + (size_t)r * 12 * 2 * 64 * 8;
        int* bcurD = cnts + (size_t)(2 * r + 0) * NBK;
        int* bcurS = cnts + (size_t)(2 * r + 1) * NBK;

        // --- edge bucketing (srcs aliases wb; both dead before spmm writes wb) ---
        bin_scatter<<<EB, 256, 0, stream>>>(src, dst, bcurD, bcurS, pairs, srcs);
        deg_dis<<<NBK, 256, 0, stream>>>(srcs, bcurS, dis);

        // layer 1: one pass over xb -> t0 (unscaled), y1', y2' (dis-scaled), all bf16
        gemm_mfma<128><<<GB, 256, 0, stream>>>(xb, 128, b1h, b1l, 0, 12, 4, 8,
                                               t0b, 64, y1b, 64, y2b, 64,
                                               nullptr, 4, dis, 0);
        spmm_lds<1><<<NBK, 512, 0, stream>>>(pairs, bcurD, y2b, y1b, wb, dis);
        spmm_lds<0><<<NBK, 512, 0, stream>>>(pairs, bcurD, wb, nullptr, zb, dis);
        ew_h<<<(NN * 32 + 255) / 256, 256, 0, stream>>>(t0b, zb, c1b + r * 64, h1, 64);
        // layer 2 (A = h1 bf16, K=64)
        gemm_mfma<64><<<GB, 256, 0, stream>>>(h1, 64, b2h, b2l, 0, 12, 4, 8,
                                              t0b, 64, y1b, 64, y2b, 64,
                                              nullptr, 4, dis, 0);
        spmm_lds<1><<<NBK, 512, 0, stream>>>(pairs, bcurD, y2b, y1b, wb, dis);
        spmm_lds<0><<<NBK, 512, 0, stream>>>(pairs, bcurD, wb, nullptr, zb, dis);
        ew_h<<<(NN * 32 + 255) / 256, 256, 0, stream>>>(t0b, zb, c2b + r * 64,
                                                        stack + r * 64, RR * 64);
    }
    gate_mfma<<<9375, 256, 0, stream>>>(stack, g1h, g1l, gb1, gw2, gb2,
                                        auxw, auxb, glogit, out);
    fuse_kernel<<<NN / 4, 256, 0, stream>>>(stack, glogit, hfused);
    gemm_mfma<64><<<GB, 256, 0, stream>>>(hfused, 64, pwh, pwl, 0, 4, 4, 8,
                                          hproj, 64, nullptr, 0, nullptr, 0,
                                          pb, 99, nullptr, 1);
    cls_mfma<<<GB, 256, 0, stream>>>(hproj, c1h, c1l, cb1, cw2, cb2, out);
}

// Round 11
// 1945.218 us; speedup vs baseline: 8.8780x; 8.8780x over previous
//
#include <hip/hip_runtime.h>
#include <hip/hip_bf16.h>

#define NN 100000
#define EE 1600000
#define RR 6
#define NBK 391        // dst/src buckets of 256 nodes
#define EB 391         // edge blocks (4096 edges each)

typedef __attribute__((ext_vector_type(8))) short bf16x8;
typedef __attribute__((ext_vector_type(4))) float f32x4;

__device__ inline short f2b(float x) {
    __hip_bfloat16 h = __float2bfloat16(x);
    return *reinterpret_cast<short*>(&h);
}
__device__ inline float b2f(short s) {
    __hip_bfloat16 h = *reinterpret_cast<__hip_bfloat16*>(&s);
    return __bfloat162float(h);
}

// ---------------- CSR build ----------------

__global__ __launch_bounds__(256) void zero_cnts(int* p, int n) {
    int i = blockIdx.x * 256 + threadIdx.x;
    if (i < n) p[i] = 0;
}

__global__ __launch_bounds__(256) void bin_count(const int* __restrict__ src,
                                                 const int* __restrict__ dst,
                                                 int* __restrict__ bcntD,
                                                 int* __restrict__ bcntS) {
    __shared__ int lcD[NBK], lcS[NBK];
    int t = threadIdx.x;
    for (int i = t; i < NBK; i += 256) { lcD[i] = 0; lcS[i] = 0; }
    __syncthreads();
    int base = blockIdx.x * 4096;
#pragma unroll
    for (int i = 0; i < 16; ++i) {
        int e = base + i * 256 + t;
        if (e < EE) {
            atomicAdd(&lcD[dst[e] >> 8], 1);
            atomicAdd(&lcS[src[e] >> 8], 1);
        }
    }
    __syncthreads();
    for (int i = t; i < NBK; i += 256) {
        if (lcD[i]) atomicAdd(&bcntD[i], lcD[i]);
        if (lcS[i]) atomicAdd(&bcntS[i], lcS[i]);
    }
}

// scatter edges into dst-bucket regions (pairs) and src-bucket regions (srcs u8).
// bucket bases re-derived in-LDS from final bcnt; chunks reserved via global bcur.
__global__ __launch_bounds__(256) void bin_scatter(const int* __restrict__ src,
                                                   const int* __restrict__ dst,
                                                   const int* __restrict__ bcntD,
                                                   const int* __restrict__ bcntS,
                                                   int* __restrict__ bcurD,
                                                   int* __restrict__ bcurS,
                                                   unsigned* __restrict__ pairs,
                                                   unsigned char* __restrict__ srcs) {
    __shared__ int bbD[NBK], bbS[NBK];
    __shared__ int lcD[NBK], lbD[NBK], loD[NBK];
    __shared__ int lcS[NBK], lbS[NBK], loS[NBK];
    int t = threadIdx.x;
    for (int i = t; i < NBK; i += 256) { lcD[i] = 0; loD[i] = 0; lcS[i] = 0; loS[i] = 0; }
    // wave 0: exclusive prefix of bcntD/bcntS into bbD/bbS
    if (t < 64) {
        int lane = t;
        int runD = 0, runS = 0;
        for (int c = 0; c < 7; ++c) {
            int i = c * 64 + lane;
            int vD = (i < NBK) ? bcntD[i] : 0;
            int vS = (i < NBK) ? bcntS[i] : 0;
            int xD = vD, xS = vS;
#pragma unroll
            for (int d = 1; d < 64; d <<= 1) {
                int yD = __shfl_up(xD, d, 64);
                int yS = __shfl_up(xS, d, 64);
                if (lane >= d) { xD += yD; xS += yS; }
            }
            if (i < NBK) { bbD[i] = runD + xD - vD; bbS[i] = runS + xS - vS; }
            runD += __shfl(xD, 63, 64);
            runS += __shfl(xS, 63, 64);
        }
    }
    __syncthreads();
    int base = blockIdx.x * 4096;
#pragma unroll
    for (int i = 0; i < 16; ++i) {
        int e = base + i * 256 + t;
        if (e < EE) {
            atomicAdd(&lcD[dst[e] >> 8], 1);
            atomicAdd(&lcS[src[e] >> 8], 1);
        }
    }
    __syncthreads();
    for (int i = t; i < NBK; i += 256) {
        lbD[i] = lcD[i] ? atomicAdd(&bcurD[i], lcD[i]) : 0;
        lbS[i] = lcS[i] ? atomicAdd(&bcurS[i], lcS[i]) : 0;
    }
    __syncthreads();
#pragma unroll
    for (int i = 0; i < 16; ++i) {
        int e = base + i * 256 + t;
        if (e < EE) {
            int s = src[e], d = dst[e];
            int bD = d >> 8, bS = s >> 8;
            int pD = bbD[bD] + lbD[bD] + atomicAdd(&loD[bD], 1);
            if (pD >= 0 && pD < EE) pairs[pD] = ((unsigned)s << 8) | (unsigned)(d & 255);
            int pS = bbS[bS] + lbS[bS] + atomicAdd(&loS[bS], 1);
            if (pS >= 0 && pS < EE) srcs[pS] = (unsigned char)(s & 255);
        }
    }
}

// one block per dst-bucket (256 rows): key = dstLocal*8 | srcSlice(src>>14).
// thread t owns row t: local scan -> rowp; LDS-cursor scatter -> csr.
__global__ __launch_bounds__(256) void csr_build(const unsigned* __restrict__ pairs,
                                                 const int* __restrict__ bcntD,
                                                 int* __restrict__ rowp,
                                                 int* __restrict__ csr) {
    __shared__ int hist[2048];
    __shared__ int wsums[4];
    __shared__ int sh_p0;
    int b = blockIdx.x, t = threadIdx.x;
    // wave 0: p0 = sum_{i<b} bcntD[i]
    if (t < 64) {
        int s = 0;
        for (int i = t; i < b; i += 64) s += bcntD[i];
#pragma unroll
        for (int d = 32; d >= 1; d >>= 1) s += __shfl_xor(s, d, 64);
        if (t == 0) sh_p0 = s;
    }
    for (int i = t; i < 2048; i += 256) hist[i] = 0;
    __syncthreads();
    int p0 = sh_p0;
    int p1 = p0 + bcntD[b];
    for (int e = p0 + t; e < p1; e += 256) {
        unsigned pr = pairs[e];
        int key = ((pr & 255) << 3) | (int)((pr >> 8) >> 14);
        atomicAdd(&hist[key], 1);
    }
    __syncthreads();
    int s[8];
    int run = 0;
#pragma unroll
    for (int i = 0; i < 8; ++i) { s[i] = run; run += hist[t * 8 + i]; }
    int lane = t & 63, wv = t >> 6;
    int x = run;
#pragma unroll
    for (int d = 1; d < 64; d <<= 1) {
        int y = __shfl_up(x, d, 64);
        if (lane >= d) x += y;
    }
    if (lane == 63) wsums[wv] = x;
    __syncthreads();
    int woff = 0;
    for (int wi = 0; wi < wv; ++wi) woff += wsums[wi];
    int excl = woff + x - run;        // exclusive prefix (within bucket) of this row
    int row = b * 256 + t;
    if (row < NN) rowp[row] = p0 + excl;
    if (b == 0 && t == 0) rowp[NN] = EE;
    __syncthreads();
#pragma unroll
    for (int i = 0; i < 8; ++i) hist[t * 8 + i] = p0 + excl + s[i];   // absolute cursors
    __syncthreads();
    for (int e = p0 + t; e < p1; e += 256) {
        unsigned pr = pairs[e];
        int key = ((pr & 255) << 3) | (int)((pr >> 8) >> 14);
        int pos = atomicAdd(&hist[key], 1);
        if (pos >= 0 && pos < EE) csr[pos] = (int)(pr >> 8);
    }
}

// one block per src-bucket: LDS hist -> dis = rsqrt(deg)
__global__ __launch_bounds__(256) void deg_dis(const unsigned char* __restrict__ srcs,
                                               const int* __restrict__ bcntS,
                                               float* __restrict__ dis) {
    __shared__ int hist[256];
    __shared__ int sh_p0;
    int b = blockIdx.x, t = threadIdx.x;
    if (t < 64) {
        int s = 0;
        for (int i = t; i < b; i += 64) s += bcntS[i];
#pragma unroll
        for (int d = 32; d >= 1; d >>= 1) s += __shfl_xor(s, d, 64);
        if (t == 0) sh_p0 = s;
    }
    hist[t] = 0;
    __syncthreads();
    int p0 = sh_p0;
    int p1 = p0 + bcntS[b];
    for (int e = p0 + t; e < p1; e += 256)
        atomicAdd(&hist[srcs[e]], 1);
    __syncthreads();
    int node = b * 256 + t;
    if (node < NN) {
        int d = hist[t];
        dis[node] = d > 0 ? rsqrtf((float)d) : 0.f;
    }
}

// ---------------- x -> bf16 once ----------------
__global__ __launch_bounds__(256) void cvt_x(const float* __restrict__ x, short* __restrict__ xb) {
    int i = blockIdx.x * 256 + threadIdx.x;   // per 8 elems
    if (i >= NN * 128 / 8) return;
    const float* p = x + (size_t)i * 8;
    float4 u0 = *(const float4*)p;
    float4 u1 = *(const float4*)(p + 4);
    bf16x8 t;
    t[0] = f2b(u0.x); t[1] = f2b(u0.y); t[2] = f2b(u0.z); t[3] = f2b(u0.w);
    t[4] = f2b(u1.x); t[5] = f2b(u1.y); t[6] = f2b(u1.z); t[7] = f2b(u1.w);
    *(bf16x8*)(xb + (size_t)i * 8) = t;
}

// ---------------- weight packing into MFMA B-fragment order, hi/lo bf16 ----------------
__global__ __launch_bounds__(256) void wpack_cheb(const float* __restrict__ W, int Kin, int KS,
                                                  short* __restrict__ bh, short* __restrict__ bl) {
    int idx = blockIdx.x * 256 + threadIdx.x;   // over R*12*KS*64
    int l = idx & 63;
    int q = idx >> 6;
    int s = q % KS; q /= KS;
    int t = q % 12; q /= 12;
    int r = q;
    if (r >= RR) return;
#pragma unroll
    for (int j = 0; j < 8; ++j) {
        int k = s * 32 + ((l >> 4) * 8) + j;
        int n = t * 16 + (l & 15);
        int g = n >> 6, jj = n & 63;
        float v = W[(((size_t)r * 3 + (g == 0 ? 0 : g)) * Kin + k) * 64 + jj];
        if (g == 0) v -= W[(((size_t)r * 3 + 2) * Kin + k) * 64 + jj];
        short hi = f2b(v);
        short lo = f2b(v - b2f(hi));
        bh[(size_t)idx * 8 + j] = hi;
        bl[(size_t)idx * 8 + j] = lo;
    }
}

__global__ __launch_bounds__(256) void wpack64(const float* __restrict__ W,
                                               short* __restrict__ bh, short* __restrict__ bl) {
    int idx = blockIdx.x * 256 + threadIdx.x;   // over 4*2*64 = 512
    if (idx >= 512) return;
    int l = idx & 63;
    int s = (idx >> 6) & 1;
    int t = idx >> 7;
#pragma unroll
    for (int j = 0; j < 8; ++j) {
        int k = s * 32 + ((l >> 4) * 8) + j;
        int n = t * 16 + (l & 15);
        float v = W[k * 64 + n];
        short hi = f2b(v);
        short lo = f2b(v - b2f(hi));
        bh[(size_t)idx * 8 + j] = hi;
        bl[(size_t)idx * 8 + j] = lo;
    }
}

// ---------------- MFMA GEMM (A bf16, up to 3 bf16 outputs) ----------------
// tiles t<s1 -> o0, t<s2 -> o1, else o2. rowscale applied only to tiles >= scale_from.
template <int KDIM>
__global__ __launch_bounds__(256) void gemm_mfma(const short* __restrict__ A, int lda,
                                                 const short* __restrict__ bph,
                                                 const short* __restrict__ bplo,
                                                 int nt0, int ntn, int s1, int s2,
                                                 short* __restrict__ o0, int ld0,
                                                 short* __restrict__ o1, int ld1,
                                                 short* __restrict__ o2, int ld2,
                                                 const float* __restrict__ bias,
                                                 int scale_from,
                                                 const float* __restrict__ rowscale,
                                                 int do_relu) {
    constexpr int KS = KDIM / 32;
    int w = threadIdx.x >> 6, l = threadIdx.x & 63;
    int rows0 = blockIdx.x * 64 + w * 16;
    int arow = rows0 + (l & 15);
    int kbase = (l >> 4) * 8;
    bf16x8 af[KS];
#pragma unroll
    for (int s = 0; s < KS; ++s) {
        bf16x8 t = {0, 0, 0, 0, 0, 0, 0, 0};
        if (arow < NN) t = *(const bf16x8*)(A + (size_t)arow * lda + s * 32 + kbase);
        af[s] = t;
    }
    for (int t = 0; t < ntn; ++t) {
        f32x4 acc = {0.f, 0.f, 0.f, 0.f};
        const short* bp0 = bph + (((size_t)(nt0 + t) * KS) * 64 + l) * 8;
        const short* bl0 = bplo + (((size_t)(nt0 + t) * KS) * 64 + l) * 8;
#pragma unroll
        for (int s = 0; s < KS; ++s) {
            bf16x8 bh = *(const bf16x8*)(bp0 + (size_t)s * 64 * 8);
            bf16x8 bl = *(const bf16x8*)(bl0 + (size_t)s * 64 * 8);
            acc = __builtin_amdgcn_mfma_f32_16x16x32_bf16(af[s], bh, acc, 0, 0, 0);
            acc = __builtin_amdgcn_mfma_f32_16x16x32_bf16(af[s], bl, acc, 0, 0, 0);
        }
        short* o;
        int ldc, tl;
        if (t < s1) { o = o0; ldc = ld0; tl = t; }
        else if (t < s2) { o = o1; ldc = ld1; tl = t - s1; }
        else { o = o2; ldc = ld2; tl = t - s2; }
        int lcol = (tl << 4) + (l & 15);
        bool scl = (rowscale != nullptr) && (t >= scale_from);
#pragma unroll
        for (int r_ = 0; r_ < 4; ++r_) {
            int row = rows0 + (l >> 4) * 4 + r_;
            if (row >= NN) continue;
            float v = acc[r_];
            if (bias) v += bias[lcol];
            if (do_relu) v = fmaxf(v, 0.f);
            if (scl) v *= rowscale[row];
            o[(size_t)row * ldc + lcol] = f2b(v);
        }
    }
}

// ---------------- SpMM: 16 lanes/row, 8B gathers, idx-prefetch pipeline ----------------
// MID=1: outb[row,:] = bf16( y1b[row,:] - 2*dis^2*sum v[src,:] )
// MID=0: outb[row,:] = bf16( -dis * sum v[src,:] )
template <int MID>
__global__ __launch_bounds__(256) void spmm_bf(const short* __restrict__ v,
                                               const short* __restrict__ y1b,
                                               short* __restrict__ outb,
                                               const int* __restrict__ csr,
                                               const int* __restrict__ rowp,
                                               const float* __restrict__ dis) {
    int t = threadIdx.x;
    int wv = t >> 6, l = t & 63;
    int g = l >> 4, fl = l & 15;              // 16-lane row-group, feat-lane (4 feats)
    int row = blockIdx.x * 16 + wv * 4 + g;   // NN divisible by 16
    int s0 = max(0, rowp[row]);
    int s1 = min(EE, rowp[row + 1]);
    float a0 = 0.f, a1 = 0.f, a2 = 0.f, a3 = 0.f;
    int e = s0;
    int idx[8], nidx[8];
    bool have = (e + 8 <= s1);
    if (have) {
#pragma unroll
        for (int i = 0; i < 8; ++i) idx[i] = csr[e + i];
    }
    while (have) {
        uint2 u[8];
#pragma unroll
        for (int i = 0; i < 8; ++i)
            u[i] = *(const uint2*)(v + (size_t)idx[i] * 64 + fl * 4);
        int en = e + 8;
        bool nhave = (en + 8 <= s1);
        if (nhave) {
#pragma unroll
            for (int i = 0; i < 8; ++i) nidx[i] = csr[en + i];   // prefetch next batch
        }
#pragma unroll
        for (int i = 0; i < 8; ++i) {
            a0 += __uint_as_float(u[i].x << 16);
            a1 += __uint_as_float(u[i].x & 0xffff0000u);
            a2 += __uint_as_float(u[i].y << 16);
            a3 += __uint_as_float(u[i].y & 0xffff0000u);
        }
#pragma unroll
        for (int i = 0; i < 8; ++i) idx[i] = nidx[i];
        e = en;
        have = nhave;
    }
    for (; e < s1; ++e) {
        uint2 u = *(const uint2*)(v + (size_t)csr[e] * 64 + fl * 4);
        a0 += __uint_as_float(u.x << 16);
        a1 += __uint_as_float(u.x & 0xffff0000u);
        a2 += __uint_as_float(u.y << 16);
        a3 += __uint_as_float(u.y & 0xffff0000u);
    }
    float d = dis[row];
    float v0, v1, v2, v3;
    if (MID) {
        uint2 yu = *(const uint2*)(y1b + (size_t)row * 64 + fl * 4);
        float mm = -2.f * d * d;
        v0 = __uint_as_float(yu.x << 16) + mm * a0;
        v1 = __uint_as_float(yu.x & 0xffff0000u) + mm * a1;
        v2 = __uint_as_float(yu.y << 16) + mm * a2;
        v3 = __uint_as_float(yu.y & 0xffff0000u) + mm * a3;
    } else {
        v0 = -d * a0; v1 = -d * a1; v2 = -d * a2; v3 = -d * a3;
    }
    uint2 o;
    o.x = (unsigned)(unsigned short)f2b(v0) | ((unsigned)(unsigned short)f2b(v1) << 16);
    o.y = (unsigned)(unsigned short)f2b(v2) | ((unsigned)(unsigned short)f2b(v3) << 16);
    *(uint2*)(outb + (size_t)row * 64 + fl * 4) = o;
}

// ---------------- elementwise: out = relu(t0 + s + bias), bf16 in/out ----------------
__global__ __launch_bounds__(256) void ew_h(const short* __restrict__ t0,
                                            const short* __restrict__ s,
                                            const float* __restrict__ bias,
                                            short* __restrict__ out, int ldc) {
    int i = blockIdx.x * 256 + threadIdx.x;   // over NN*32 u32 groups
    if (i >= NN * 32) return;
    int row = i >> 5, c2 = (i & 31) * 2;
    unsigned a = *(const unsigned*)(t0 + (size_t)row * 64 + c2);
    unsigned b = *(const unsigned*)(s + (size_t)row * 64 + c2);
    float v0 = __uint_as_float(a << 16) + __uint_as_float(b << 16) + bias[c2];
    float v1 = __uint_as_float(a & 0xffff0000u) + __uint_as_float(b & 0xffff0000u) + bias[c2 + 1];
    v0 = fmaxf(v0, 0.f);
    v1 = fmaxf(v1, 0.f);
    unsigned o = (unsigned)(unsigned short)f2b(v0) | ((unsigned)(unsigned short)f2b(v1) << 16);
    *(unsigned*)(out + (size_t)row * ldc + c2) = o;
}

// ---------------- gate via MFMA (+ fused aux outputs) ----------------
__global__ __launch_bounds__(256) void gate_mfma(const short* __restrict__ stack,
                                                 const short* __restrict__ g1h,
                                                 const short* __restrict__ g1l,
                                                 const float* __restrict__ gb1,
                                                 const float* __restrict__ gw2,
                                                 const float* __restrict__ gb2,
                                                 const float* __restrict__ auxw,
                                                 const float* __restrict__ auxb,
                                                 float* __restrict__ glogit,
                                                 float* __restrict__ out) {
    int w = threadIdx.x >> 6, l = threadIdx.x & 63;
    int rows0 = blockIdx.x * 64 + w * 16;      // 9375*64 == 600000 exactly
    int arow = rows0 + (l & 15);
    int kbase = (l >> 4) * 8;
    bf16x8 af[2];
#pragma unroll
    for (int s = 0; s < 2; ++s)
        af[s] = *(const bf16x8*)(stack + (size_t)arow * 64 + s * 32 + kbase);
    int rmod = arow % RR;
    float paux = 0.f;
#pragma unroll
    for (int s = 0; s < 2; ++s) {
        const float* aw = auxw + rmod * 64 + s * 32 + kbase;
#pragma unroll
        for (int j = 0; j < 8; ++j) paux = fmaf(b2f(af[s][j]), aw[j], paux);
    }
    paux += __shfl_xor(paux, 16, 64);
    paux += __shfl_xor(paux, 32, 64);
    if (l < 16) out[NN + (size_t)rows0 + l] = paux + auxb[rmod];
    float p[4] = {0.f, 0.f, 0.f, 0.f};
#pragma unroll
    for (int t = 0; t < 4; ++t) {
        f32x4 acc = {0.f, 0.f, 0.f, 0.f};
#pragma unroll
        for (int s = 0; s < 2; ++s) {
            bf16x8 bh = *(const bf16x8*)(g1h + (((size_t)t * 2 + s) * 64 + l) * 8);
            bf16x8 bl = *(const bf16x8*)(g1l + (((size_t)t * 2 + s) * 64 + l) * 8);
            acc = __builtin_amdgcn_mfma_f32_16x16x32_bf16(af[s], bh, acc, 0, 0, 0);
            acc = __builtin_amdgcn_mfma_f32_16x16x32_bf16(af[s], bl, acc, 0, 0, 0);
        }
        int col = t * 16 + (l & 15);
        float b = gb1[col], w2 = gw2[col];
#pragma unroll
        for (int r_ = 0; r_ < 4; ++r_) {
            float h = fmaxf(acc[r_] + b, 0.f);
            p[r_] = fmaf(h, w2, p[r_]);
        }
    }
#pragma unroll
    for (int d = 1; d < 16; d <<= 1) {
#pragma unroll
        for (int r_ = 0; r_ < 4; ++r_) p[r_] += __shfl_xor(p[r_], d, 64);
    }
    if ((l & 15) == 0) {
        float g2 = gb2[0];
#pragma unroll
        for (int r_ = 0; r_ < 4; ++r_) glogit[rows0 + (l >> 4) * 4 + r_] = p[r_] + g2;
    }
}

// ---------------- fuse: softmax over R -> h_fused (bf16) ----------------
__global__ __launch_bounds__(256) void fuse_kernel(const short* __restrict__ stack,
                                                   const float* __restrict__ glogit,
                                                   short* __restrict__ hfused) {
    int tid = threadIdx.x;
    int w = tid >> 6, lane = tid & 63;
    int n = blockIdx.x * 4 + w;
    if (n >= NN) return;
    float gl[RR];
    float m = -1e30f;
#pragma unroll
    for (int r = 0; r < RR; r++) {
        gl[r] = glogit[(size_t)n * RR + r];
        m = fmaxf(m, gl[r]);
    }
    float ssum = 0.f;
#pragma unroll
    for (int r = 0; r < RR; r++) {
        gl[r] = __expf(gl[r] - m);
        ssum += gl[r];
    }
    float inv = 1.f / ssum;
    float hf = 0.f;
#pragma unroll
    for (int r = 0; r < RR; r++) {
        float s = b2f(stack[((size_t)n * RR + r) * 64 + lane]);
        hf = fmaf(gl[r] * inv, s, hf);
    }
    hfused[(size_t)n * 64 + lane] = f2b(hf);
}

// ---------------- cls via MFMA ----------------
__global__ __launch_bounds__(256) void cls_mfma(const short* __restrict__ hproj,
                                                const short* __restrict__ c1h,
                                                const short* __restrict__ c1l,
                                                const float* __restrict__ cb1,
                                                const float* __restrict__ cw2,
                                                const float* __restrict__ cb2,
                                                float* __restrict__ out) {
    int w = threadIdx.x >> 6, l = threadIdx.x & 63;
    int rows0 = blockIdx.x * 64 + w * 16;
    int arow = rows0 + (l & 15);
    int kbase = (l >> 4) * 8;
    bf16x8 af[2];
#pragma unroll
    for (int s = 0; s < 2; ++s) {
        bf16x8 t = {0, 0, 0, 0, 0, 0, 0, 0};
        if (arow < NN) t = *(const bf16x8*)(hproj + (size_t)arow * 64 + s * 32 + kbase);
        af[s] = t;
    }
    float p[4] = {0.f, 0.f, 0.f, 0.f};
#pragma unroll
    for (int t = 0; t < 4; ++t) {
        f32x4 acc = {0.f, 0.f, 0.f, 0.f};
#pragma unroll
        for (int s = 0; s < 2; ++s) {
            bf16x8 bh = *(const bf16x8*)(c1h + (((size_t)t * 2 + s) * 64 + l) * 8);
            bf16x8 bl = *(const bf16x8*)(c1l + (((size_t)t * 2 + s) * 64 + l) * 8);
            acc = __builtin_amdgcn_mfma_f32_16x16x32_bf16(af[s], bh, acc, 0, 0, 0);
            acc = __builtin_amdgcn_mfma_f32_16x16x32_bf16(af[s], bl, acc, 0, 0, 0);
        }
        int col = t * 16 + (l & 15);
        float b = cb1[col], w2 = cw2[col];
#pragma unroll
        for (int r_ = 0; r_ < 4; ++r_) {
            float h = fmaxf(acc[r_] + b, 0.f);
            p[r_] = fmaf(h, w2, p[r_]);
        }
    }
#pragma unroll
    for (int d = 1; d < 16; d <<= 1) {
#pragma unroll
        for (int r_ = 0; r_ < 4; ++r_) p[r_] += __shfl_xor(p[r_], d, 64);
    }
    if ((l & 15) == 0) {
        float c2 = cb2[0];
#pragma unroll
        for (int r_ = 0; r_ < 4; ++r_) {
            int row = rows0 + (l >> 4) * 4 + r_;
            if (row < NN) out[row] = p[r_] + c2;
        }
    }
}

// ---------------- host ----------------

extern "C" void kernel_launch(void* const* d_in, const int* in_sizes, int n_in,
                              void* d_out, int out_size, void* d_ws, size_t ws_size,
                              hipStream_t stream) {
    const float* x = (const float*)d_in[0];
    const int* ei = (const int*)d_in[1];
    const float* c1w = (const float*)d_in[2];
    const float* c1b = (const float*)d_in[3];
    const float* c2w = (const float*)d_in[4];
    const float* c2b = (const float*)d_in[5];
    const float* gw1 = (const float*)d_in[6];
    const float* gb1 = (const float*)d_in[7];
    const float* gw2 = (const float*)d_in[8];
    const float* gb2 = (const float*)d_in[9];
    const float* pw = (const float*)d_in[10];
    const float* pb = (const float*)d_in[11];
    const float* cw1 = (const float*)d_in[12];
    const float* cb1 = (const float*)d_in[13];
    const float* cw2 = (const float*)d_in[14];
    const float* cb2 = (const float*)d_in[15];
    const float* auxw = (const float*)d_in[16];
    const float* auxb = (const float*)d_in[17];
    float* out = (float*)d_out;

    char* wsp = (char*)d_ws;
    size_t off = 0;
    auto carve = [&](size_t bytes) -> char* {
        char* p = wsp + off;
        off += (bytes + 255) & ~(size_t)255;
        return p;
    };
    short* stack = (short*)carve((size_t)NN * RR * 64 * 2);   // bf16 [N][R][64]
    short* y1b = (short*)carve((size_t)NN * 64 * 2);          // y1' bf16; aliases zb, pairs
    short* y2b = (short*)carve((size_t)NN * 64 * 2);          // y2' bf16; aliases srcs, hproj
    short* wb = (short*)carve((size_t)NN * 64 * 2);           // w' bf16
    short* h1 = (short*)carve((size_t)NN * 64 * 2);           // bf16; also hfused
    short* t0b = (short*)carve((size_t)NN * 64 * 2);          // x@(W0-W2) bf16
    short* xb = (short*)carve((size_t)NN * 128 * 2);          // x as bf16
    float* dis = (float*)carve((size_t)NN * 4);
    int* rowp = (int*)carve((size_t)(NN + 1) * 4);
    int* csr = (int*)carve((size_t)EE * 4);
    int* cnts = (int*)carve((size_t)4 * RR * NBK * 4);        // bcntD|bcntS|bcurD|bcurS per rel
    short* bp1h = (short*)carve((size_t)RR * 12 * 4 * 64 * 8 * 2);
    short* bp1l = (short*)carve((size_t)RR * 12 * 4 * 64 * 8 * 2);
    short* bp2h = (short*)carve((size_t)RR * 12 * 2 * 64 * 8 * 2);
    short* bp2l = (short*)carve((size_t)RR * 12 * 2 * 64 * 8 * 2);
    short* g1h = (short*)carve((size_t)512 * 8 * 2);
    short* g1l = (short*)carve((size_t)512 * 8 * 2);
    short* pwh = (short*)carve((size_t)512 * 8 * 2);
    short* pwl = (short*)carve((size_t)512 * 8 * 2);
    short* c1h = (short*)carve((size_t)512 * 8 * 2);
    short* c1l = (short*)carve((size_t)512 * 8 * 2);
    float* glogit = (float*)carve((size_t)NN * RR * 4);
    short* zb = y1b;                                  // alias: y1' consumed by spmm<1> first
    unsigned* pairs = (unsigned*)y1b;                 // EE u32 = 6.4MB <= y1b 12.8MB
    unsigned char* srcs = (unsigned char*)y2b;        // EE u8 = 1.6MB <= y2b 12.8MB
    short* hfused = h1;       // alias: h1 dead after relation loop
    short* hproj = y2b;       // alias: y2b dead after relation loop
    (void)in_sizes; (void)n_in; (void)out_size;

    if (off > ws_size) return;   // guard: clean absmax-fail => ws too small

    zero_cnts<<<(4 * RR * NBK + 255) / 256, 256, 0, stream>>>(cnts, 4 * RR * NBK);
    cvt_x<<<(NN * 128 / 8 + 255) / 256, 256, 0, stream>>>(x, xb);
    wpack_cheb<<<72, 256, 0, stream>>>(c1w, 128, 4, bp1h, bp1l);
    wpack_cheb<<<36, 256, 0, stream>>>(c2w, 64, 2, bp2h, bp2l);
    wpack64<<<2, 256, 0, stream>>>(gw1, g1h, g1l);
    wpack64<<<2, 256, 0, stream>>>(pw, pwh, pwl);
    wpack64<<<2, 256, 0, stream>>>(cw1, c1h, c1l);

    const int GB = 1563;   // ceil(NN/64)
    for (int r = 0; r < RR; ++r) {
        const int* src = ei + (size_t)r * 2 * EE;
        const int* dst = src + EE;
        const short* b1h = bp1h + (size_t)r * 12 * 4 * 64 * 8;
        const short* b1l = bp1l + (size_t)r * 12 * 4 * 64 * 8;
        const short* b2h = bp2h + (size_t)r * 12 * 2 * 64 * 8;
        const short* b2l = bp2l + (size_t)r * 12 * 2 * 64 * 8;
        int* bcntD = cnts + (size_t)(4 * r + 0) * NBK;
        int* bcntS = cnts + (size_t)(4 * r + 1) * NBK;
        int* bcurD = cnts + (size_t)(4 * r + 2) * NBK;
        int* bcurS = cnts + (size_t)(4 * r + 3) * NBK;

        // --- CSR build (pairs/srcs live in y1b/y2b space, dead before gemm writes them) ---
        bin_count<<<EB, 256, 0, stream>>>(src, dst, bcntD, bcntS);
        bin_scatter<<<EB, 256, 0, stream>>>(src, dst, bcntD, bcntS, bcurD, bcurS, pairs, srcs);
        csr_build<<<NBK, 256, 0, stream>>>(pairs, bcntD, rowp, csr);
        deg_dis<<<NBK, 256, 0, stream>>>(srcs, bcntS, dis);

        // layer 1: one pass over xb -> t0 (unscaled), y1', y2' (dis-scaled), all bf16
        gemm_mfma<128><<<GB, 256, 0, stream>>>(xb, 128, b1h, b1l, 0, 12, 4, 8,
                                               t0b, 64, y1b, 64, y2b, 64,
                                               nullptr, 4, dis, 0);
        spmm_bf<1><<<NN / 16, 256, 0, stream>>>(y2b, y1b, wb, csr, rowp, dis);
        spmm_bf<0><<<NN / 16, 256, 0, stream>>>(wb, nullptr, zb, csr, rowp, dis);
        ew_h<<<(NN * 32 + 255) / 256, 256, 0, stream>>>(t0b, zb, c1b + r * 64, h1, 64);
        // layer 2 (A = h1 bf16, K=64)
        gemm_mfma<64><<<GB, 256, 0, stream>>>(h1, 64, b2h, b2l, 0, 12, 4, 8,
                                              t0b, 64, y1b, 64, y2b, 64,
                                              nullptr, 4, dis, 0);
        spmm_bf<1><<<NN / 16, 256, 0, stream>>>(y2b, y1b, wb, csr, rowp, dis);
        spmm_bf<0><<<NN / 16, 256, 0, stream>>>(wb, nullptr, zb, csr, rowp, dis);
        ew_h<<<(NN * 32 + 255) / 256, 256, 0, stream>>>(t0b, zb, c2b + r * 64,
                                                        stack + r * 64, RR * 64);
    }
    gate_mfma<<<9375, 256, 0, stream>>>(stack, g1h, g1l, gb1, gw2, gb2,
                                        auxw, auxb, glogit, out);
    fuse_kernel<<<NN / 4, 256, 0, stream>>>(stack, glogit, hfused);
    gemm_mfma<64><<<GB, 256, 0, stream>>>(hfused, 64, pwh, pwl, 0, 4, 4, 8,
                                          hproj, 64, nullptr, 0, nullptr, 0,
                                          pb, 99, nullptr, 1);
    cls_mfma<<<GB, 256, 0, stream>>>(hproj, c1h, c1l, cb1, cw2, cb2, out);
}

// Round 12
// 1711.240 us; speedup vs baseline: 10.0919x; 1.1367x over previous
//
#include <hip/hip_runtime.h>
#include <hip/hip_bf16.h>

#define NN 100000
#define EE 1600000
#define RR 6
#define NBK 391        // dst/src buckets of 256 nodes
#define EB 391         // edge blocks (4096 edges each)
#define CAP 4608       // per-bucket edge capacity (mean 4096, +8 sigma)

typedef __attribute__((ext_vector_type(8))) short bf16x8;
typedef __attribute__((ext_vector_type(4))) float f32x4;

__device__ inline short f2b(float x) {
    __hip_bfloat16 h = __float2bfloat16(x);
    return *reinterpret_cast<short*>(&h);
}
__device__ inline float b2f(short s) {
    __hip_bfloat16 h = *reinterpret_cast<__hip_bfloat16*>(&s);
    return __bfloat162float(h);
}

// ---------------- edge bucketing (fixed-capacity, no pre-count) ----------------

__global__ __launch_bounds__(256) void zero_cnts(int* p, int n) {
    int i = blockIdx.x * 256 + threadIdx.x;
    if (i < n) p[i] = 0;
}

// scatter edges into CAP-sized dst-bucket regions (pairs: src<<8|dstLocal) and
// src-bucket regions (srcs u8); LDS chunk aggregation, cursors give final counts.
__global__ __launch_bounds__(256) void bin_scatter(const int* __restrict__ src,
                                                   const int* __restrict__ dst,
                                                   int* __restrict__ bcurD,
                                                   int* __restrict__ bcurS,
                                                   unsigned* __restrict__ pairs,
                                                   unsigned char* __restrict__ srcs) {
    __shared__ int lcD[NBK], lbD[NBK], loD[NBK];
    __shared__ int lcS[NBK], lbS[NBK], loS[NBK];
    int t = threadIdx.x;
    for (int i = t; i < NBK; i += 256) { lcD[i] = 0; loD[i] = 0; lcS[i] = 0; loS[i] = 0; }
    __syncthreads();
    int base = blockIdx.x * 4096;
#pragma unroll
    for (int i = 0; i < 16; ++i) {
        int e = base + i * 256 + t;
        if (e < EE) {
            atomicAdd(&lcD[dst[e] >> 8], 1);
            atomicAdd(&lcS[src[e] >> 8], 1);
        }
    }
    __syncthreads();
    for (int i = t; i < NBK; i += 256) {
        lbD[i] = lcD[i] ? atomicAdd(&bcurD[i], lcD[i]) : 0;
        lbS[i] = lcS[i] ? atomicAdd(&bcurS[i], lcS[i]) : 0;
    }
    __syncthreads();
#pragma unroll
    for (int i = 0; i < 16; ++i) {
        int e = base + i * 256 + t;
        if (e < EE) {
            int s = src[e], d = dst[e];
            int bD = d >> 8, bS = s >> 8;
            int pD = lbD[bD] + atomicAdd(&loD[bD], 1);
            if (pD >= 0 && pD < CAP)
                pairs[(size_t)bD * CAP + pD] = ((unsigned)s << 8) | (unsigned)(d & 255);
            int pS = lbS[bS] + atomicAdd(&loS[bS], 1);
            if (pS >= 0 && pS < CAP)
                srcs[(size_t)bS * CAP + pS] = (unsigned char)(s & 255);
        }
    }
}

// one block per dst-bucket: key = dstLocal*8 | srcSlice(src>>14); LDS hist -> scan ->
// rowp2 (257 entries per bucket, absolute into CAP-padded csr) -> LDS-cursor scatter.
__global__ __launch_bounds__(512) void csr_build(const unsigned* __restrict__ pairs,
                                                 const int* __restrict__ bcurD,
                                                 int* __restrict__ rowp2,
                                                 int* __restrict__ csr) {
    __shared__ int hist[2048];
    __shared__ int wsums[4];
    int b = blockIdx.x, t = threadIdx.x;
    int p0 = b * CAP;
    int cnt = min(bcurD[b], CAP);
    int p1 = p0 + cnt;
    for (int i = t; i < 2048; i += 512) hist[i] = 0;
    __syncthreads();
    for (int e = p0 + t; e < p1; e += 512) {
        unsigned pr = pairs[e];
        int key = ((pr & 255) << 3) | (int)((pr >> 8) >> 14);
        atomicAdd(&hist[key], 1);
    }
    __syncthreads();
    int s[8] = {0, 0, 0, 0, 0, 0, 0, 0};
    int run = 0, x = 0;
    int lane = t & 63, wv = t >> 6;
    if (t < 256) {
#pragma unroll
        for (int i = 0; i < 8; ++i) { s[i] = run; run += hist[t * 8 + i]; }
        x = run;
#pragma unroll
        for (int d = 1; d < 64; d <<= 1) {
            int y = __shfl_up(x, d, 64);
            if (lane >= d) x += y;
        }
        if (lane == 63) wsums[wv] = x;
    }
    __syncthreads();
    if (t < 256) {
        int woff = 0;
        for (int wi = 0; wi < wv; ++wi) woff += wsums[wi];
        int excl = woff + x - run;
        rowp2[b * 257 + t] = p0 + excl;
        if (t == 0) rowp2[b * 257 + 256] = p1;
#pragma unroll
        for (int i = 0; i < 8; ++i) hist[t * 8 + i] = p0 + excl + s[i];   // absolute cursors
    }
    __syncthreads();
    for (int e = p0 + t; e < p1; e += 512) {
        unsigned pr = pairs[e];
        int key = ((pr & 255) << 3) | (int)((pr >> 8) >> 14);
        int pos = atomicAdd(&hist[key], 1);
        if (pos >= 0 && pos < NBK * CAP) csr[pos] = (int)(pr >> 8);
    }
}

// one block per src-bucket: LDS hist -> dis = rsqrt(deg)
__global__ __launch_bounds__(256) void deg_dis(const unsigned char* __restrict__ srcs,
                                               const int* __restrict__ bcurS,
                                               float* __restrict__ dis) {
    __shared__ int hist[256];
    int b = blockIdx.x, t = threadIdx.x;
    hist[t] = 0;
    __syncthreads();
    int cnt = min(bcurS[b], CAP);
    const unsigned char* sp = srcs + (size_t)b * CAP;
    for (int e = t; e < cnt; e += 256)
        atomicAdd(&hist[sp[e]], 1);
    __syncthreads();
    int node = b * 256 + t;
    if (node < NN) {
        int d = hist[t];
        dis[node] = d > 0 ? rsqrtf((float)d) : 0.f;
    }
}

// ---------------- x -> bf16 once ----------------
__global__ __launch_bounds__(256) void cvt_x(const float* __restrict__ x, short* __restrict__ xb) {
    int i = blockIdx.x * 256 + threadIdx.x;   // per 8 elems
    if (i >= NN * 128 / 8) return;
    const float* p = x + (size_t)i * 8;
    float4 u0 = *(const float4*)p;
    float4 u1 = *(const float4*)(p + 4);
    bf16x8 t;
    t[0] = f2b(u0.x); t[1] = f2b(u0.y); t[2] = f2b(u0.z); t[3] = f2b(u0.w);
    t[4] = f2b(u1.x); t[5] = f2b(u1.y); t[6] = f2b(u1.z); t[7] = f2b(u1.w);
    *(bf16x8*)(xb + (size_t)i * 8) = t;
}

// ---------------- weight packing into MFMA B-fragment order, hi/lo bf16 ----------------
__global__ __launch_bounds__(256) void wpack_cheb(const float* __restrict__ W, int Kin, int KS,
                                                  short* __restrict__ bh, short* __restrict__ bl) {
    int idx = blockIdx.x * 256 + threadIdx.x;   // over R*12*KS*64
    int l = idx & 63;
    int q = idx >> 6;
    int s = q % KS; q /= KS;
    int t = q % 12; q /= 12;
    int r = q;
    if (r >= RR) return;
#pragma unroll
    for (int j = 0; j < 8; ++j) {
        int k = s * 32 + ((l >> 4) * 8) + j;
        int n = t * 16 + (l & 15);
        int g = n >> 6, jj = n & 63;
        float v = W[(((size_t)r * 3 + (g == 0 ? 0 : g)) * Kin + k) * 64 + jj];
        if (g == 0) v -= W[(((size_t)r * 3 + 2) * Kin + k) * 64 + jj];
        short hi = f2b(v);
        short lo = f2b(v - b2f(hi));
        bh[(size_t)idx * 8 + j] = hi;
        bl[(size_t)idx * 8 + j] = lo;
    }
}

__global__ __launch_bounds__(256) void wpack64(const float* __restrict__ W,
                                               short* __restrict__ bh, short* __restrict__ bl) {
    int idx = blockIdx.x * 256 + threadIdx.x;   // over 4*2*64 = 512
    if (idx >= 512) return;
    int l = idx & 63;
    int s = (idx >> 6) & 1;
    int t = idx >> 7;
#pragma unroll
    for (int j = 0; j < 8; ++j) {
        int k = s * 32 + ((l >> 4) * 8) + j;
        int n = t * 16 + (l & 15);
        float v = W[k * 64 + n];
        short hi = f2b(v);
        short lo = f2b(v - b2f(hi));
        bh[(size_t)idx * 8 + j] = hi;
        bl[(size_t)idx * 8 + j] = lo;
    }
}

// ---------------- MFMA GEMM (A bf16, up to 3 bf16 outputs) ----------------
template <int KDIM>
__global__ __launch_bounds__(256) void gemm_mfma(const short* __restrict__ A, int lda,
                                                 const short* __restrict__ bph,
                                                 const short* __restrict__ bplo,
                                                 int nt0, int ntn, int s1, int s2,
                                                 short* __restrict__ o0, int ld0,
                                                 short* __restrict__ o1, int ld1,
                                                 short* __restrict__ o2, int ld2,
                                                 const float* __restrict__ bias,
                                                 int scale_from,
                                                 const float* __restrict__ rowscale,
                                                 int do_relu) {
    constexpr int KS = KDIM / 32;
    int w = threadIdx.x >> 6, l = threadIdx.x & 63;
    int rows0 = blockIdx.x * 64 + w * 16;
    int arow = rows0 + (l & 15);
    int kbase = (l >> 4) * 8;
    bf16x8 af[KS];
#pragma unroll
    for (int s = 0; s < KS; ++s) {
        bf16x8 t = {0, 0, 0, 0, 0, 0, 0, 0};
        if (arow < NN) t = *(const bf16x8*)(A + (size_t)arow * lda + s * 32 + kbase);
        af[s] = t;
    }
    for (int t = 0; t < ntn; ++t) {
        f32x4 acc = {0.f, 0.f, 0.f, 0.f};
        const short* bp0 = bph + (((size_t)(nt0 + t) * KS) * 64 + l) * 8;
        const short* bl0 = bplo + (((size_t)(nt0 + t) * KS) * 64 + l) * 8;
#pragma unroll
        for (int s = 0; s < KS; ++s) {
            bf16x8 bh = *(const bf16x8*)(bp0 + (size_t)s * 64 * 8);
            bf16x8 bl = *(const bf16x8*)(bl0 + (size_t)s * 64 * 8);
            acc = __builtin_amdgcn_mfma_f32_16x16x32_bf16(af[s], bh, acc, 0, 0, 0);
            acc = __builtin_amdgcn_mfma_f32_16x16x32_bf16(af[s], bl, acc, 0, 0, 0);
        }
        short* o;
        int ldc, tl;
        if (t < s1) { o = o0; ldc = ld0; tl = t; }
        else if (t < s2) { o = o1; ldc = ld1; tl = t - s1; }
        else { o = o2; ldc = ld2; tl = t - s2; }
        int lcol = (tl << 4) + (l & 15);
        bool scl = (rowscale != nullptr) && (t >= scale_from);
#pragma unroll
        for (int r_ = 0; r_ < 4; ++r_) {
            int row = rows0 + (l >> 4) * 4 + r_;
            if (row >= NN) continue;
            float v = acc[r_];
            if (bias) v += bias[lcol];
            if (do_relu) v = fmaxf(v, 0.f);
            if (scl) v *= rowscale[row];
            o[(size_t)row * ldc + lcol] = f2b(v);
        }
    }
}

// ---------------- SpMM: 16 lanes/row, 8B gathers, idx-prefetch pipeline ----------------
// MID=1: outb[row,:] = bf16( aux[row,:] - 2*dis^2 * sum v[src,:] )          (aux=y1)
// MID=0: outb[row,:] = bf16( relu(aux[row,:] + (-dis)*sum v[src,:] + bias) ) (aux=t0)
template <int MID>
__global__ __launch_bounds__(256) void spmm_bf(const short* __restrict__ v,
                                               const short* __restrict__ aux,
                                               short* __restrict__ outb, int ldc,
                                               const int* __restrict__ csr,
                                               const int* __restrict__ rowp2,
                                               const float* __restrict__ dis,
                                               const float* __restrict__ bias) {
    int t = threadIdx.x;
    int wv = t >> 6, l = t & 63;
    int g = l >> 4, fl = l & 15;              // 16-lane row-group, feat-lane (4 feats)
    int row = blockIdx.x * 16 + wv * 4 + g;   // NN divisible by 16
    int b = row >> 8, ri = row & 255;
    int s0 = rowp2[b * 257 + ri];
    int s1 = rowp2[b * 257 + ri + 1];
    s0 = max(s0, b * CAP);
    s1 = min(s1, b * CAP + CAP);
    float a0 = 0.f, a1 = 0.f, a2 = 0.f, a3 = 0.f;
    int e = s0;
    int idx[8], nidx[8];
    bool have = (e + 8 <= s1);
    if (have) {
#pragma unroll
        for (int i = 0; i < 8; ++i) idx[i] = csr[e + i];
    }
    while (have) {
        uint2 u[8];
#pragma unroll
        for (int i = 0; i < 8; ++i)
            u[i] = *(const uint2*)(v + (size_t)idx[i] * 64 + fl * 4);
        int en = e + 8;
        bool nhave = (en + 8 <= s1);
        if (nhave) {
#pragma unroll
            for (int i = 0; i < 8; ++i) nidx[i] = csr[en + i];   // prefetch next batch
        }
#pragma unroll
        for (int i = 0; i < 8; ++i) {
            a0 += __uint_as_float(u[i].x << 16);
            a1 += __uint_as_float(u[i].x & 0xffff0000u);
            a2 += __uint_as_float(u[i].y << 16);
            a3 += __uint_as_float(u[i].y & 0xffff0000u);
        }
#pragma unroll
        for (int i = 0; i < 8; ++i) idx[i] = nidx[i];
        e = en;
        have = nhave;
    }
    for (; e < s1; ++e) {
        uint2 u = *(const uint2*)(v + (size_t)csr[e] * 64 + fl * 4);
        a0 += __uint_as_float(u.x << 16);
        a1 += __uint_as_float(u.x & 0xffff0000u);
        a2 += __uint_as_float(u.y << 16);
        a3 += __uint_as_float(u.y & 0xffff0000u);
    }
    float d = dis[row];
    uint2 au = *(const uint2*)(aux + (size_t)row * 64 + fl * 4);
    float v0, v1, v2, v3;
    if (MID) {
        float mm = -2.f * d * d;
        v0 = __uint_as_float(au.x << 16) + mm * a0;
        v1 = __uint_as_float(au.x & 0xffff0000u) + mm * a1;
        v2 = __uint_as_float(au.y << 16) + mm * a2;
        v3 = __uint_as_float(au.y & 0xffff0000u) + mm * a3;
    } else {
        float4 bs = *(const float4*)(bias + fl * 4);
        v0 = fmaxf(__uint_as_float(au.x << 16) - d * a0 + bs.x, 0.f);
        v1 = fmaxf(__uint_as_float(au.x & 0xffff0000u) - d * a1 + bs.y, 0.f);
        v2 = fmaxf(__uint_as_float(au.y << 16) - d * a2 + bs.z, 0.f);
        v3 = fmaxf(__uint_as_float(au.y & 0xffff0000u) - d * a3 + bs.w, 0.f);
    }
    uint2 o;
    o.x = (unsigned)(unsigned short)f2b(v0) | ((unsigned)(unsigned short)f2b(v1) << 16);
    o.y = (unsigned)(unsigned short)f2b(v2) | ((unsigned)(unsigned short)f2b(v3) << 16);
    *(uint2*)(outb + (size_t)row * ldc + fl * 4) = o;
}

// ---------------- gate via MFMA (+ fused aux outputs) ----------------
__global__ __launch_bounds__(256) void gate_mfma(const short* __restrict__ stack,
                                                 const short* __restrict__ g1h,
                                                 const short* __restrict__ g1l,
                                                 const float* __restrict__ gb1,
                                                 const float* __restrict__ gw2,
                                                 const float* __restrict__ gb2,
                                                 const float* __restrict__ auxw,
                                                 const float* __restrict__ auxb,
                                                 float* __restrict__ glogit,
                                                 float* __restrict__ out) {
    int w = threadIdx.x >> 6, l = threadIdx.x & 63;
    int rows0 = blockIdx.x * 64 + w * 16;      // 9375*64 == 600000 exactly
    int arow = rows0 + (l & 15);
    int kbase = (l >> 4) * 8;
    bf16x8 af[2];
#pragma unroll
    for (int s = 0; s < 2; ++s)
        af[s] = *(const bf16x8*)(stack + (size_t)arow * 64 + s * 32 + kbase);
    int rmod = arow % RR;
    float paux = 0.f;
#pragma unroll
    for (int s = 0; s < 2; ++s) {
        const float* aw = auxw + rmod * 64 + s * 32 + kbase;
#pragma unroll
        for (int j = 0; j < 8; ++j) paux = fmaf(b2f(af[s][j]), aw[j], paux);
    }
    paux += __shfl_xor(paux, 16, 64);
    paux += __shfl_xor(paux, 32, 64);
    if (l < 16) out[NN + (size_t)rows0 + l] = paux + auxb[rmod];
    float p[4] = {0.f, 0.f, 0.f, 0.f};
#pragma unroll
    for (int t = 0; t < 4; ++t) {
        f32x4 acc = {0.f, 0.f, 0.f, 0.f};
#pragma unroll
        for (int s = 0; s < 2; ++s) {
            bf16x8 bh = *(const bf16x8*)(g1h + (((size_t)t * 2 + s) * 64 + l) * 8);
            bf16x8 bl = *(const bf16x8*)(g1l + (((size_t)t * 2 + s) * 64 + l) * 8);
            acc = __builtin_amdgcn_mfma_f32_16x16x32_bf16(af[s], bh, acc, 0, 0, 0);
            acc = __builtin_amdgcn_mfma_f32_16x16x32_bf16(af[s], bl, acc, 0, 0, 0);
        }
        int col = t * 16 + (l & 15);
        float b = gb1[col], w2 = gw2[col];
#pragma unroll
        for (int r_ = 0; r_ < 4; ++r_) {
            float h = fmaxf(acc[r_] + b, 0.f);
            p[r_] = fmaf(h, w2, p[r_]);
        }
    }
#pragma unroll
    for (int d = 1; d < 16; d <<= 1) {
#pragma unroll
        for (int r_ = 0; r_ < 4; ++r_) p[r_] += __shfl_xor(p[r_], d, 64);
    }
    if ((l & 15) == 0) {
        float g2 = gb2[0];
#pragma unroll
        for (int r_ = 0; r_ < 4; ++r_) glogit[rows0 + (l >> 4) * 4 + r_] = p[r_] + g2;
    }
}

// ---------------- fuse: softmax over R -> h_fused (bf16) ----------------
__global__ __launch_bounds__(256) void fuse_kernel(const short* __restrict__ stack,
                                                   const float* __restrict__ glogit,
                                                   short* __restrict__ hfused) {
    int tid = threadIdx.x;
    int w = tid >> 6, lane = tid & 63;
    int n = blockIdx.x * 4 + w;
    if (n >= NN) return;
    float gl[RR];
    float m = -1e30f;
#pragma unroll
    for (int r = 0; r < RR; r++) {
        gl[r] = glogit[(size_t)n * RR + r];
        m = fmaxf(m, gl[r]);
    }
    float ssum = 0.f;
#pragma unroll
    for (int r = 0; r < RR; r++) {
        gl[r] = __expf(gl[r] - m);
        ssum += gl[r];
    }
    float inv = 1.f / ssum;
    float hf = 0.f;
#pragma unroll
    for (int r = 0; r < RR; r++) {
        float s = b2f(stack[((size_t)n * RR + r) * 64 + lane]);
        hf = fmaf(gl[r] * inv, s, hf);
    }
    hfused[(size_t)n * 64 + lane] = f2b(hf);
}

// ---------------- cls via MFMA ----------------
__global__ __launch_bounds__(256) void cls_mfma(const short* __restrict__ hproj,
                                                const short* __restrict__ c1h,
                                                const short* __restrict__ c1l,
                                                const float* __restrict__ cb1,
                                                const float* __restrict__ cw2,
                                                const float* __restrict__ cb2,
                                                float* __restrict__ out) {
    int w = threadIdx.x >> 6, l = threadIdx.x & 63;
    int rows0 = blockIdx.x * 64 + w * 16;
    int arow = rows0 + (l & 15);
    int kbase = (l >> 4) * 8;
    bf16x8 af[2];
#pragma unroll
    for (int s = 0; s < 2; ++s) {
        bf16x8 t = {0, 0, 0, 0, 0, 0, 0, 0};
        if (arow < NN) t = *(const bf16x8*)(hproj + (size_t)arow * 64 + s * 32 + kbase);
        af[s] = t;
    }
    float p[4] = {0.f, 0.f, 0.f, 0.f};
#pragma unroll
    for (int t = 0; t < 4; ++t) {
        f32x4 acc = {0.f, 0.f, 0.f, 0.f};
#pragma unroll
        for (int s = 0; s < 2; ++s) {
            bf16x8 bh = *(const bf16x8*)(c1h + (((size_t)t * 2 + s) * 64 + l) * 8);
            bf16x8 bl = *(const bf16x8*)(c1l + (((size_t)t * 2 + s) * 64 + l) * 8);
            acc = __builtin_amdgcn_mfma_f32_16x16x32_bf16(af[s], bh, acc, 0, 0, 0);
            acc = __builtin_amdgcn_mfma_f32_16x16x32_bf16(af[s], bl, acc, 0, 0, 0);
        }
        int col = t * 16 + (l & 15);
        float b = cb1[col], w2 = cw2[col];
#pragma unroll
        for (int r_ = 0; r_ < 4; ++r_) {
            float h = fmaxf(acc[r_] + b, 0.f);
            p[r_] = fmaf(h, w2, p[r_]);
        }
    }
#pragma unroll
    for (int d = 1; d < 16; d <<= 1) {
#pragma unroll
        for (int r_ = 0; r_ < 4; ++r_) p[r_] += __shfl_xor(p[r_], d, 64);
    }
    if ((l & 15) == 0) {
        float c2 = cb2[0];
#pragma unroll
        for (int r_ = 0; r_ < 4; ++r_) {
            int row = rows0 + (l >> 4) * 4 + r_;
            if (row < NN) out[row] = p[r_] + c2;
        }
    }
}

// ---------------- host ----------------

extern "C" void kernel_launch(void* const* d_in, const int* in_sizes, int n_in,
                              void* d_out, int out_size, void* d_ws, size_t ws_size,
                              hipStream_t stream) {
    const float* x = (const float*)d_in[0];
    const int* ei = (const int*)d_in[1];
    const float* c1w = (const float*)d_in[2];
    const float* c1b = (const float*)d_in[3];
    const float* c2w = (const float*)d_in[4];
    const float* c2b = (const float*)d_in[5];
    const float* gw1 = (const float*)d_in[6];
    const float* gb1 = (const float*)d_in[7];
    const float* gw2 = (const float*)d_in[8];
    const float* gb2 = (const float*)d_in[9];
    const float* pw = (const float*)d_in[10];
    const float* pb = (const float*)d_in[11];
    const float* cw1 = (const float*)d_in[12];
    const float* cb1 = (const float*)d_in[13];
    const float* cw2 = (const float*)d_in[14];
    const float* cb2 = (const float*)d_in[15];
    const float* auxw = (const float*)d_in[16];
    const float* auxb = (const float*)d_in[17];
    float* out = (float*)d_out;

    char* wsp = (char*)d_ws;
    size_t off = 0;
    auto carve = [&](size_t bytes) -> char* {
        char* p = wsp + off;
        off += (bytes + 255) & ~(size_t)255;
        return p;
    };
    short* stack = (short*)carve((size_t)NN * RR * 64 * 2);   // bf16 [N][R][64]
    short* y1b = (short*)carve((size_t)NN * 64 * 2);          // y1' bf16; aliases pairs
    short* y2b = (short*)carve((size_t)NN * 64 * 2);          // y2' bf16; aliases srcs, hproj
    short* wb = (short*)carve((size_t)NN * 64 * 2);           // w' bf16
    short* h1 = (short*)carve((size_t)NN * 64 * 2);           // bf16; also hfused
    short* t0b = (short*)carve((size_t)NN * 64 * 2);          // x@(W0-W2) bf16
    short* xb = (short*)carve((size_t)NN * 128 * 2);          // x as bf16
    float* dis = (float*)carve((size_t)NN * 4);
    int* rowp2 = (int*)carve((size_t)NBK * 257 * 4);
    int* csr = (int*)carve((size_t)NBK * CAP * 4);
    int* cnts = (int*)carve((size_t)2 * RR * NBK * 4);        // bcurD|bcurS per relation
    short* bp1h = (short*)carve((size_t)RR * 12 * 4 * 64 * 8 * 2);
    short* bp1l = (short*)carve((size_t)RR * 12 * 4 * 64 * 8 * 2);
    short* bp2h = (short*)carve((size_t)RR * 12 * 2 * 64 * 8 * 2);
    short* bp2l = (short*)carve((size_t)RR * 12 * 2 * 64 * 8 * 2);
    short* g1h = (short*)carve((size_t)512 * 8 * 2);
    short* g1l = (short*)carve((size_t)512 * 8 * 2);
    short* pwh = (short*)carve((size_t)512 * 8 * 2);
    short* pwl = (short*)carve((size_t)512 * 8 * 2);
    short* c1h = (short*)carve((size_t)512 * 8 * 2);
    short* c1l = (short*)carve((size_t)512 * 8 * 2);
    float* glogit = (float*)carve((size_t)NN * RR * 4);
    unsigned* pairs = (unsigned*)y1b;                 // NBK*CAP u32 = 7.2MB <= y1b 12.8MB
    unsigned char* srcs = (unsigned char*)y2b;        // NBK*CAP u8 = 1.8MB <= y2b 12.8MB
    short* hfused = h1;       // alias: h1 dead after relation loop
    short* hproj = y2b;       // alias: y2b dead after relation loop
    (void)in_sizes; (void)n_in; (void)out_size;

    if (off > ws_size) return;   // guard: clean absmax-fail => ws too small

    zero_cnts<<<(2 * RR * NBK + 255) / 256, 256, 0, stream>>>(cnts, 2 * RR * NBK);
    cvt_x<<<(NN * 128 / 8 + 255) / 256, 256, 0, stream>>>(x, xb);
    wpack_cheb<<<72, 256, 0, stream>>>(c1w, 128, 4, bp1h, bp1l);
    wpack_cheb<<<36, 256, 0, stream>>>(c2w, 64, 2, bp2h, bp2l);
    wpack64<<<2, 256, 0, stream>>>(gw1, g1h, g1l);
    wpack64<<<2, 256, 0, stream>>>(pw, pwh, pwl);
    wpack64<<<2, 256, 0, stream>>>(cw1, c1h, c1l);

    const int GB = 1563;   // ceil(NN/64)
    for (int r = 0; r < RR; ++r) {
        const int* src = ei + (size_t)r * 2 * EE;
        const int* dst = src + EE;
        const short* b1h = bp1h + (size_t)r * 12 * 4 * 64 * 8;
        const short* b1l = bp1l + (size_t)r * 12 * 4 * 64 * 8;
        const short* b2h = bp2h + (size_t)r * 12 * 2 * 64 * 8;
        const short* b2l = bp2l + (size_t)r * 12 * 2 * 64 * 8;
        int* bcurD = cnts + (size_t)(2 * r + 0) * NBK;
        int* bcurS = cnts + (size_t)(2 * r + 1) * NBK;

        // --- edge bucketing (pairs/srcs live in y1b/y2b space, dead before gemm) ---
        bin_scatter<<<EB, 256, 0, stream>>>(src, dst, bcurD, bcurS, pairs, srcs);
        csr_build<<<NBK, 512, 0, stream>>>(pairs, bcurD, rowp2, csr);
        deg_dis<<<NBK, 256, 0, stream>>>(srcs, bcurS, dis);

        // layer 1: one pass over xb -> t0 (unscaled), y1', y2' (dis-scaled), all bf16
        gemm_mfma<128><<<GB, 256, 0, stream>>>(xb, 128, b1h, b1l, 0, 12, 4, 8,
                                               t0b, 64, y1b, 64, y2b, 64,
                                               nullptr, 4, dis, 0);
        spmm_bf<1><<<NN / 16, 256, 0, stream>>>(y2b, y1b, wb, 64, csr, rowp2, dis, nullptr);
        spmm_bf<0><<<NN / 16, 256, 0, stream>>>(wb, t0b, h1, 64, csr, rowp2, dis,
                                                c1b + r * 64);
        // layer 2 (A = h1 bf16, K=64)
        gemm_mfma<64><<<GB, 256, 0, stream>>>(h1, 64, b2h, b2l, 0, 12, 4, 8,
                                              t0b, 64, y1b, 64, y2b, 64,
                                              nullptr, 4, dis, 0);
        spmm_bf<1><<<NN / 16, 256, 0, stream>>>(y2b, y1b, wb, 64, csr, rowp2, dis, nullptr);
        spmm_bf<0><<<NN / 16, 256, 0, stream>>>(wb, t0b, stack + r * 64, RR * 64,
                                                csr, rowp2, dis, c2b + r * 64);
    }
    gate_mfma<<<9375, 256, 0, stream>>>(stack, g1h, g1l, gb1, gw2, gb2,
                                        auxw, auxb, glogit, out);
    fuse_kernel<<<NN / 4, 256, 0, stream>>>(stack, glogit, hfused);
    gemm_mfma<64><<<GB, 256, 0, stream>>>(hfused, 64, pwh, pwl, 0, 4, 4, 8,
                                          hproj, 64, nullptr, 0, nullptr, 0,
                                          pb, 99, nullptr, 1);
    cls_mfma<<<GB, 256, 0, stream>>>(hproj, c1h, c1l, cb1, cw2, cb2, out);
}